// Round 13
// baseline (4993.698 us; speedup 1.0000x reference)
//
#include <hip/hip_runtime.h>
#include <math.h>

typedef double double2v __attribute__((ext_vector_type(2)));
typedef double double4v __attribute__((ext_vector_type(4)));
typedef float  float4v  __attribute__((ext_vector_type(4)));

#if defined(__has_builtin)
#if __has_builtin(__builtin_amdgcn_mfma_f64_16x16x4f64)
#define HAVE_MFMA_F64 1
#endif
#endif

// ===================== JAX Threefry-2x32 (bit-exact) =====================
__device__ __forceinline__ void threefry2x32(unsigned k0, unsigned k1,
                                             unsigned x0, unsigned x1,
                                             unsigned& o0, unsigned& o1)
{
  unsigned ks2 = k0 ^ k1 ^ 0x1BD11BDAu;
  x0 += k0; x1 += k1;
#define TFR(r) { x0 += x1; x1 = (x1 << r) | (x1 >> (32 - r)); x1 ^= x0; }
  TFR(13) TFR(15) TFR(26) TFR(6)
  x0 += k1;  x1 += ks2 + 1u;
  TFR(17) TFR(29) TFR(16) TFR(24)
  x0 += ks2; x1 += k0 + 2u;
  TFR(13) TFR(15) TFR(26) TFR(6)
  x0 += k0;  x1 += k1 + 3u;
  TFR(17) TFR(29) TFR(16) TFR(24)
  x0 += k1;  x1 += ks2 + 4u;
  TFR(13) TFR(15) TFR(26) TFR(6)
  x0 += ks2; x1 += k0 + 5u;
#undef TFR
  o0 = x0; o1 = x1;
}

// jax_threefry_partitionable=True: word e = o0 ^ o1 of block (0, e)
__device__ __forceinline__ unsigned rand_word(unsigned kA, unsigned kB, unsigned e)
{
  unsigned o0, o1;
  threefry2x32(kA, kB, 0u, e, o0, o1);
  return o0 ^ o1;
}

__device__ __forceinline__ float bits_to_unit(unsigned bits)
{
  unsigned u = (bits >> 9) | 0x3f800000u;
  return __uint_as_float(u) - 1.0f;   // exact, in [0,1)
}

// erfinv in double: Giles poly init + 1 Halley iteration on erf()
__device__ __forceinline__ double erfinv_d(double x)
{
  double w = -log((1.0 - x) * (1.0 + x));
  double p;
  if (w < 5.0) {
    w -= 2.5;
    p = 2.81022636e-08;
    p = fma(p, w, 3.43273939e-07);
    p = fma(p, w, -3.5233877e-06);
    p = fma(p, w, -4.39150654e-06);
    p = fma(p, w, 0.00021858087);
    p = fma(p, w, -0.00125372503);
    p = fma(p, w, -0.00417768164);
    p = fma(p, w, 0.246640727);
    p = fma(p, w, 1.50140941);
  } else {
    w = sqrt(w) - 3.0;
    p = -0.000200214257;
    p = fma(p, w, 0.000100950558);
    p = fma(p, w, 0.00134934322);
    p = fma(p, w, -0.00367342844);
    p = fma(p, w, 0.00573950773);
    p = fma(p, w, -0.0076224613);
    p = fma(p, w, 0.00943887047);
    p = fma(p, w, 1.00167406);
    p = fma(p, w, 2.83297682);
  }
  double r = p * x;
  double f  = erf(r) - x;
  double fp = 1.1283791670955126 * exp(-r * r);   // 2/sqrt(pi) e^{-r^2}
  double q  = f / fp;
  return r - q / (1.0 + r * q);
}

// N(0,1) sample e of a jax.random.normal(f32) draw
__device__ __forceinline__ double eps_normal(unsigned kA, unsigned kB, unsigned e)
{
  float f = bits_to_unit(rand_word(kA, kB, e));
  double u = (double)f * (2.0 - 5.9604644775390625e-8)
           - (1.0 - 5.9604644775390625e-8);
  return 1.4142135623730951 * erfinv_d(u);
}

__device__ __forceinline__ double sigd(double x) { return 1.0 / (1.0 + exp(-x)); }

__device__ __forceinline__ double gumbel_d(unsigned kA, unsigned kB, unsigned e)
{
  float f = bits_to_unit(rand_word(kA, kB, e));
  double u = (f == 0.0f) ? 1.1754943508222875e-38 : (double)f;
  return -log(-log(u));
}

// ===================== setup kernels =====================
__global__ void k_keys(unsigned* keys)
{
  if (threadIdx.x != 0 || blockIdx.x != 0) return;
  unsigned a0,a1,b0,b1,c0,c1,d0,d1;
  unsigned kx = 0u, ky = 42u;                 // jax.random.key(42)
  threefry2x32(kx, ky, 0u, 0u, a0, a1);       // carried key
  threefry2x32(kx, ky, 0u, 1u, b0, b1);       // k0 (h0 uniform)
  keys[0] = b0; keys[1] = b1;
  kx = a0; ky = a1;
  for (int s = 0; s < 100; ++s) {
    threefry2x32(kx, ky, 0u, 0u, a0, a1);     // k
    threefry2x32(kx, ky, 0u, 1u, c0, c1);     // ke
    threefry2x32(kx, ky, 0u, 2u, d0, d1);     // kr
    keys[2 + 4*s + 0] = c0; keys[2 + 4*s + 1] = c1;
    keys[2 + 4*s + 2] = d0; keys[2 + 4*s + 3] = d1;
    kx = a0; ky = a1;
  }
}

__global__ __launch_bounds__(256) void k_prep(
    const float* fcz_w, const float* fcz_b, const float* fcr_w, const float* fcr_b,
    const float* fcn_w, const float* fcn_b, const float* fco_w, const float* fco_b,
    const float* h2l_w, const float* h2l_b,
    double* wzrT, double* wnT, double* wo, double* bz, double* br,
    double* bnn, double* bo, double* h2lw, double* h2lb)
{
  int id = blockIdx.x * 256 + threadIdx.x;
  if (id < 65536) {
    int k = id >> 8, j = id & 255;
    wzrT[id] = (double)((j < 128) ? fcz_w[j*256 + k] : fcr_w[(j-128)*256 + k]);
    return;
  }
  id -= 65536;
  if (id < 65536) { int k = id >> 8, j = id & 255; wnT[id] = (double)fcn_w[j*256 + k]; return; }
  id -= 65536;
  if (id < 256) { wo[id] = (double)fco_w[id]; return; }
  id -= 256;
  if (id < 128) { bz[id] = (double)fcz_b[id]; return; }
  id -= 128;
  if (id < 128) { br[id] = (double)fcr_b[id]; return; }
  id -= 128;
  if (id < 256) { bnn[id] = (double)fcn_b[id]; return; }
  id -= 256;
  if (id < 1) { bo[0] = (double)fco_b[0]; return; }
  id -= 1;
  if (id < 384) { h2lw[id] = (double)h2l_w[id]; return; }
  id -= 384;
  if (id < 3) { h2lb[id] = (double)h2l_b[id]; return; }
}

__global__ __launch_bounds__(256) void k_h0(const unsigned* keys, double* h, double* p)
{
  unsigned e = blockIdx.x * 256 + threadIdx.x;    // < 524288
  h[e] = (double)bits_to_unit(rand_word(keys[0], keys[1], e));
  if (e < 4096) p[e] = (double)(float)log(1.0 / 128.0);
}

// ===================== frontend (map CNN encoder) =====================
__global__ __launch_bounds__(256) void k_conv1(const float* in, const float* w, double* out)
{
  int bc = blockIdx.x; int b = bc >> 4, co = bc & 15;
  __shared__ double wl[25];
  __shared__ float plf[4096];
  if (threadIdx.x < 25) wl[threadIdx.x] = (double)w[co*25 + threadIdx.x];
  const float* ib = in + (size_t)b * 4096;
  for (int j = 0; j < 16; ++j) plf[threadIdx.x + j*256] = ib[threadIdx.x + j*256];
  __syncthreads();
  for (int q = 0; q < 4; ++q) {
    int px = q*256 + threadIdx.x;
    int oh = px >> 5, ow = px & 31;
    double acc = 0.0;
    for (int kh = 0; kh < 5; ++kh) {
      int ih = oh*2 - 2 + kh; if (ih < 0 || ih >= 64) continue;
      for (int kw = 0; kw < 5; ++kw) {
        int iw = ow*2 - 2 + kw; if (iw < 0 || iw >= 64) continue;
        acc = fma((double)plf[ih*64 + iw], wl[kh*5 + kw], acc);
      }
    }
    out[((size_t)b*16 + co)*1024 + px] = fmax(acc, 0.0);
  }
}

// 4 output channels per block: input planes read once per quad
__global__ __launch_bounds__(256) void k_conv3x3(const double* in, const float* w,
                                                 double* out, int Ci, int Co)
{
  int bc = blockIdx.x; int b = bc / (Co >> 2), cog = bc % (Co >> 2);
  int co0 = cog * 4;
  __shared__ double wl[4][288];
  __shared__ double pl[2][1024];
  for (int idx = threadIdx.x; idx < 4*Ci*9; idx += 256) {
    int c = idx / (Ci*9), e = idx % (Ci*9);
    wl[c][e] = (double)w[(size_t)(co0 + c)*Ci*9 + e];
  }
  double acc[4][4];
  #pragma unroll
  for (int q = 0; q < 4; ++q)
    #pragma unroll
    for (int c = 0; c < 4; ++c) acc[q][c] = 0.0;
  const double* ib = in + (size_t)b * Ci * 1024;
  for (int q = 0; q < 4; ++q)
    pl[0][threadIdx.x + q*256] = ib[threadIdx.x + q*256];
  __syncthreads();
  for (int ci = 0; ci < Ci; ++ci) {
    int cur = ci & 1;
    if (ci + 1 < Ci) {
      for (int q = 0; q < 4; ++q)
        pl[cur ^ 1][threadIdx.x + q*256] = ib[(ci + 1)*1024 + threadIdx.x + q*256];
    }
    for (int q = 0; q < 4; ++q) {
      int px = q*256 + threadIdx.x;
      int oh = px >> 5, ow = px & 31;
      for (int kh = 0; kh < 3; ++kh) {
        int ih = oh - 1 + kh; if (ih < 0 || ih >= 32) continue;
        for (int kw = 0; kw < 3; ++kw) {
          int iw = ow - 1 + kw; if (iw < 0 || iw >= 32) continue;
          double pv = pl[cur][ih*32 + iw];
          #pragma unroll
          for (int c = 0; c < 4; ++c)
            acc[q][c] = fma(pv, wl[c][ci*9 + kh*3 + kw], acc[q][c]);
        }
      }
    }
    __syncthreads();
  }
  for (int q = 0; q < 4; ++q) {
    int px = q*256 + threadIdx.x;
    #pragma unroll
    for (int c = 0; c < 4; ++c)
      out[((size_t)b*Co + co0 + c)*1024 + px] = fmax(acc[q][c], 0.0);
  }
}

__global__ __launch_bounds__(256) void k_bnstats1(const double* __restrict__ x,
    double* __restrict__ partS, double* __restrict__ partS2, int C)
{
  int c = blockIdx.x >> 3, chunk = blockIdx.x & 7;
  double s = 0.0, s2 = 0.0;
  for (int e = threadIdx.x; e < 4096; e += 256) {
    int b = chunk*4 + (e >> 10), px = e & 1023;
    double v = x[((size_t)b*C + c)*1024 + px];
    s += v; s2 = fma(v, v, s2);
  }
  __shared__ double rs[256], rs2[256];
  rs[threadIdx.x] = s; rs2[threadIdx.x] = s2;
  __syncthreads();
  for (int d = 128; d; d >>= 1) {
    if (threadIdx.x < d) { rs[threadIdx.x] += rs[threadIdx.x + d]; rs2[threadIdx.x] += rs2[threadIdx.x + d]; }
    __syncthreads();
  }
  if (threadIdx.x == 0) { partS[blockIdx.x] = rs[0]; partS2[blockIdx.x] = rs2[0]; }
}

__global__ void k_bnstats2(const double* __restrict__ partS,
                           const double* __restrict__ partS2,
                           const float* g, const float* bta, double* scsh, int C)
{
  int c = threadIdx.x;
  if (c >= C) return;
  double s = 0.0, s2 = 0.0;
  for (int j = 0; j < 8; ++j) { s += partS[c*8 + j]; s2 += partS2[c*8 + j]; }
  double n = 32768.0;
  double mean = s / n;
  double var = s2 / n - mean*mean;
  double sc = (double)g[c] / sqrt(var + 1e-5);
  scsh[c*2] = sc;
  scsh[c*2 + 1] = (double)bta[c] - mean * sc;
}

__global__ __launch_bounds__(256) void k_bnapply(double* x, const double* scsh, int C)
{
  size_t e = (size_t)blockIdx.x * 256 + threadIdx.x;
  int c = (int)((e >> 10) % (size_t)C);
  x[e] = fma(x[e], scsh[c*2], scsh[c*2 + 1]);
}

// vectorized: 4 consecutive elements/thread/iter (float4 weights, double4 x)
__global__ __launch_bounds__(256) void k_mapfc(const double* x, const float* w,
                                               const float* bias, double* emb)
{
  int blk = blockIdx.x; int b = blk >> 4, jg = blk & 15;
  double acc[8];
  #pragma unroll
  for (int jj = 0; jj < 8; ++jj) acc[jj] = 0.0;
  const double* xb = x + (size_t)b * 32768;
  for (int j = 0; j < 32; ++j) {
    int e4 = (threadIdx.x + j*256) << 2;
    double4v xv = *(const double4v*)&xb[e4];
    #pragma unroll
    for (int jj = 0; jj < 8; ++jj) {
      float4v wv = *(const float4v*)&w[(size_t)(jg*8 + jj)*32768 + e4];
      double a = acc[jj];
      a = fma(xv.x, (double)wv.x, a);
      a = fma(xv.y, (double)wv.y, a);
      a = fma(xv.z, (double)wv.z, a);
      a = fma(xv.w, (double)wv.w, a);
      acc[jj] = a;
    }
  }
  __shared__ double red[8][256];
  #pragma unroll
  for (int jj = 0; jj < 8; ++jj) red[jj][threadIdx.x] = acc[jj];
  __syncthreads();
  for (int d = 128; d; d >>= 1) {
    if (threadIdx.x < d)
      #pragma unroll
      for (int jj = 0; jj < 8; ++jj) red[jj][threadIdx.x] += red[jj][threadIdx.x + d];
    __syncthreads();
  }
  if (threadIdx.x < 8) {
    int j = jg*8 + threadIdx.x;
    emb[b*128 + j] = fmax(red[threadIdx.x][0] + (double)bias[j], 0.0);
  }
}

__global__ void k_maps(const double* emb, const float* m2o_w, const float* m2o_b,
                       const float* m2a_w, const float* m2a_b,
                       double* omap, double* amap)
{
  int b = blockIdx.x, j = threadIdx.x;   // 64 threads
  double a1 = (double)m2o_b[j], a2 = (double)m2a_b[j];
  for (int k = 0; k < 128; ++k) {
    double ev = emb[b*128 + k];
    a1 = fma(ev, (double)m2o_w[j*128 + k], a1);
    a2 = fma(ev, (double)m2a_w[j*128 + k], a2);
  }
  omap[b*64 + j] = fmax(a1, 0.0);
  amap[b*64 + j] = fmax(a2, 0.0);
}

__global__ __launch_bounds__(128) void k_xs(const float* obs_in, const float* act_in,
                                            const float* obs_w, const float* obs_b,
                                            const float* act_w, const float* act_b,
                                            const double* omap, const double* amap,
                                            const double* wo,
                                            double* xs, double* xo)
{
  int s = blockIdx.x, b = blockIdx.y, j = threadIdx.x;
  double v;
  if (j < 64) {
    double a = (double)obs_b[j];
    const float* o = obs_in + ((size_t)b*100 + s)*16;
    for (int k = 0; k < 16; ++k) a = fma((double)o[k], (double)obs_w[j*16 + k], a);
    v = fmax(a, 0.0) * omap[b*64 + j];
  } else {
    int j2 = j - 64;
    double a = (double)act_b[j2];
    const float* o = act_in + ((size_t)b*100 + s)*3;
    for (int k = 0; k < 3; ++k) a = fma((double)o[k], (double)act_w[j2*3 + k], a);
    v = fmax(a, 0.0) * amap[b*64 + j2];
  }
  xs[((size_t)s*32 + b)*128 + j] = v;
  __shared__ double red[128];
  red[j] = v * wo[128 + j];
  __syncthreads();
  for (int d = 64; d; d >>= 1) {
    if (j < d) red[j] += red[j + d];
    __syncthreads();
  }
  if (j == 0) xo[s*32 + b] = red[0];
}

__global__ __launch_bounds__(256, 2) void k_xpre2(const double* __restrict__ xs,
    const double* __restrict__ wzrT, const double* __restrict__ wnT,
    double* __restrict__ xzr, double* __restrict__ xn)
{
  int s = blockIdx.x >> 2, bg = blockIdx.x & 3;
  __shared__ double xl[8][128];
  int t = threadIdx.x;
  #pragma unroll
  for (int j = 0; j < 4; ++j) {
    int e = t + j*256;
    int i = e >> 7, cc = e & 127;
    xl[i][cc] = xs[((size_t)s*32 + bg*8 + i)*128 + cc];
  }
  __syncthreads();
  double az[8], an[8];
  #pragma unroll
  for (int i = 0; i < 8; ++i) { az[i] = 0.0; an[i] = 0.0; }
  for (int k = 0; k < 128; ++k) {
    double wz = wzrT[k*256 + t];
    double wn = wnT[(128 + k)*256 + t];
    #pragma unroll
    for (int i = 0; i < 8; ++i) {
      double xv = xl[i][k];
      az[i] = fma(xv, wz, az[i]);
      an[i] = fma(xv, wn, an[i]);
    }
  }
  #pragma unroll
  for (int i = 0; i < 8; ++i) {
    size_t sb = (size_t)s*32 + bg*8 + i;
    xzr[sb*256 + t] = az[i];
    xn [sb*256 + t] = an[i];
  }
}

// ===================== fused scan step (f64 MFMA, layout flag=1 verified) ==
// 256 blocks x 512 threads; 16 rows/block.  Wave wv owns cols wv*16..+15
// (and +128).  D layout (probe-verified on gfx950): q -> row = kgrp + 4q,
// col = mrow.  z/mu/var/eps/h1 thread-local.
__global__ __launch_bounds__(512, 4) void k_step(
    const double* __restrict__ hsrc, const int* __restrict__ idxp,
    const double* __restrict__ xzr, const double* __restrict__ xn,
    const double* __restrict__ xo,
    const double* __restrict__ wzrT, const double* __restrict__ wnT,
    const double* __restrict__ bz, const double* __restrict__ br,
    const double* __restrict__ bnn, const double* __restrict__ wo,
    const double* __restrict__ bo, double* __restrict__ P,
    const double* __restrict__ h2lw, const double* __restrict__ h2lb,
    double* __restrict__ h1out, double* __restrict__ LP,
    const double* __restrict__ PNPRE,
    float* __restrict__ pfout, float* __restrict__ yout,
    const unsigned* __restrict__ keys, int s)
{
  __shared__ double ah[16][130];   // gathered h
  __shared__ double aw[16][130];   // rg*h, later h1
  __shared__ double wsh[128], ys[128], red8[8][128];
  __shared__ int    isx[128];
  __shared__ double smx[2], ssx[2];
  const int t  = threadIdx.x;
  const int r0 = blockIdx.x * 16;
  const int wv = t >> 6, lane = t & 63;
  const bool first = (idxp == nullptr);

  // ---- phase C of step s-1 (blocks 0..31): pn normalize + y ----
  if (!first && blockIdx.x < 32) {
    int b = blockIdx.x;
    if (t < 128) {
      double q = PNPRE[b*128 + t];
      double m = q;
      for (int d = 32; d; d >>= 1) m = fmax(m, __shfl_xor(m, d, 64));
      if ((t & 63) == 0) smx[t >> 6] = m;
    }
    __syncthreads();
    if (t < 128) {
      double q = PNPRE[b*128 + t];
      double m = fmax(smx[0], smx[1]);
      double e = exp(q - m), su = e;
      for (int d = 32; d; d >>= 1) su += __shfl_xor(su, d, 64);
      if ((t & 63) == 0) ssx[t >> 6] = su;
    }
    __syncthreads();
    if (t < 128) {
      double q = PNPRE[b*128 + t];
      double m = fmax(smx[0], smx[1]);
      double pn = q - (m + log(ssx[0] + ssx[1]));
      P[b*128 + t] = pn;
      wsh[t] = exp(pn);
      isx[t] = idxp[t*32 + b];
    }
    __syncthreads();
    {
      #pragma unroll
      for (int colh = 0; colh < 2; ++colh) {
        int col = lane + colh*64;
        double acc = 0.0;
        for (int q = 0; q < 16; ++q) {
          int ii = wv*16 + q;
          acc = fma(wsh[ii], hsrc[(size_t)(isx[ii]*32 + b)*128 + col], acc);
        }
        red8[wv][col] = acc;
      }
    }
    __syncthreads();
    if (t < 128) {
      double a = red8[0][t];
      for (int gg = 1; gg < 8; ++gg) a += red8[gg][t];
      ys[t] = a;
    }
    __syncthreads();
    if (t < 3) {
      double dsum = h2lb[t];
      for (int cc = 0; cc < 128; ++cc)
        dsum = fma(h2lw[t*128 + cc], ys[cc], dsum);
      yout[(s - 1)*96 + b*3 + t] = (float)(1.0 / (1.0 + exp(-dsum)));
    }
    __syncthreads();
  }

  // ---- gather prev h (4 elements/thread, coalesced) ----
  #pragma unroll
  for (int j = 0; j < 4; ++j) {
    int e = t + j*512;
    int r = e >> 7, cc = e & 127;
    int R = r0 + r, b = R & 31;
    int src = first ? R : (idxp[R]*32 + b);
    ah[r][cc] = hsrc[(size_t)src*128 + cc];
  }
  __syncthreads();
  // ---- pf for previous step: 8 waves x 2 rows ----
  if (pfout != nullptr) {
    #pragma unroll
    for (int q = 0; q < 2; ++q) {
      int i = wv*2 + q;
      double v0 = ah[i][lane*2], v1 = ah[i][lane*2 + 1];
      double s0 = fma(v0, h2lw[lane*2],       v1 * h2lw[lane*2 + 1]);
      double s1 = fma(v0, h2lw[128 + lane*2], v1 * h2lw[128 + lane*2 + 1]);
      double s2 = fma(v0, h2lw[256 + lane*2], v1 * h2lw[256 + lane*2 + 1]);
      for (int d = 32; d; d >>= 1) {
        s0 += __shfl_xor(s0, d, 64);
        s1 += __shfl_xor(s1, d, 64);
        s2 += __shfl_xor(s2, d, 64);
      }
      if (lane == 0) {
        float* o = pfout + (r0 + i) * 3;
        o[0] = (float)(1.0 / (1.0 + exp(-(s0 + h2lb[0]))));
        o[1] = (float)(1.0 / (1.0 + exp(-(s1 + h2lb[1]))));
        o[2] = (float)(1.0 / (1.0 + exp(-(s2 + h2lb[2]))));
      }
    }
  }

#ifdef HAVE_MFMA_F64
  const int mrow = lane & 15;
  const int kgrp = lane >> 4;
  const int col  = wv*16 + mrow;           // this thread's output column
  // ---- GEMM1: h-part of [x|h] @ Wzr^T ----
  double4v acc0 = {0.0, 0.0, 0.0, 0.0};
  double4v acc1 = {0.0, 0.0, 0.0, 0.0};
  for (int k4 = 0; k4 < 32; ++k4) {
    int k = k4*4 + kgrp;
    double a  = ah[mrow][k];
    double b0 = wzrT[(size_t)(128 + k)*256 + col];
    double b1 = wzrT[(size_t)(128 + k)*256 + 128 + col];
    acc0 = __builtin_amdgcn_mfma_f64_16x16x4f64(a, b0, acc0, 0, 0, 0);
    acc1 = __builtin_amdgcn_mfma_f64_16x16x4f64(a, b1, acc1, 0, 0, 0);
  }
  double zq[4];
  #pragma unroll
  for (int q = 0; q < 4; ++q) {
    int row = kgrp + 4*q;
    int b = (r0 + row) & 31;
    zq[q] = sigd(acc0[q] + xzr[b*256 + col] + bz[col]);
    double rgv = sigd(acc1[q] + xzr[b*256 + 128 + col] + br[col]);
    aw[row][col] = rgv * ah[row][col];
  }
  __syncthreads();
  // ---- GEMM2: (rg*h)-part of [rg*h|x] @ Wn^T ----
  acc0 = double4v{0.0, 0.0, 0.0, 0.0};
  acc1 = double4v{0.0, 0.0, 0.0, 0.0};
  for (int k4 = 0; k4 < 32; ++k4) {
    int k = k4*4 + kgrp;
    double a  = aw[mrow][k];
    double b0 = wnT[(size_t)k*256 + col];
    double b1 = wnT[(size_t)k*256 + 128 + col];
    acc0 = __builtin_amdgcn_mfma_f64_16x16x4f64(a, b0, acc0, 0, 0, 0);
    acc1 = __builtin_amdgcn_mfma_f64_16x16x4f64(a, b1, acc1, 0, 0, 0);
  }
  // thread-local reparam + h1
  double hq[4];
  {
    unsigned keA = keys[2 + 4*s], keB = keys[2 + 4*s + 1];
    #pragma unroll
    for (int q = 0; q < 4; ++q) {
      int row = kgrp + 4*q;
      int b = (r0 + row) & 31, R = r0 + row;
      double mu  = acc0[q] + xn[b*256 + col] + bnn[col];
      double var = acc1[q] + xn[b*256 + 128 + col] + bnn[128 + col];
      double sp = fmax(var, 0.0) + log1p(exp(-fabs(var)));
      double ep = eps_normal(keA, keB, (unsigned)(R*128 + col));
      double n  = fma(ep, sp, mu);
      double hv = (1.0 - zq[q])*n + zq[q]*ah[row][col];
      h1out[(size_t)R*128 + col] = hv;
      hq[q] = hv;
    }
  }
  __syncthreads();   // all GEMM2 aw reads complete
  #pragma unroll
  for (int q = 0; q < 4; ++q) aw[kgrp + 4*q][col] = hq[q];
#else
  // compile-time fallback: vector path (R9 bit-exact)
  {
    const int rq = t >> 7;
    const int c2 = t & 127;
    double ac0[4], ac1[4];
    #pragma unroll
    for (int i = 0; i < 4; ++i) { ac0[i] = 0.0; ac1[i] = 0.0; }
    for (int k = 0; k < 128; ++k) {
      double w0 = wzrT[(size_t)(128 + k)*256 + c2];
      double w1 = wzrT[(size_t)(128 + k)*256 + 128 + c2];
      #pragma unroll
      for (int i = 0; i < 4; ++i) {
        double av = ah[rq*4 + i][k];
        ac0[i] = fma(av, w0, ac0[i]);
        ac1[i] = fma(av, w1, ac1[i]);
      }
    }
    double zrv[4];
    #pragma unroll
    for (int i = 0; i < 4; ++i) {
      int row = rq*4 + i, b = (r0 + row) & 31;
      zrv[i] = sigd(ac0[i] + xzr[b*256 + c2] + bz[c2]);
      double rgv = sigd(ac1[i] + xzr[b*256 + c2 + 128] + br[c2]);
      aw[row][c2] = rgv * ah[row][c2];
    }
    __syncthreads();
    #pragma unroll
    for (int i = 0; i < 4; ++i) { ac0[i] = 0.0; ac1[i] = 0.0; }
    for (int k = 0; k < 128; ++k) {
      double w0 = wnT[(size_t)k*256 + c2];
      double w1 = wnT[(size_t)k*256 + 128 + c2];
      #pragma unroll
      for (int i = 0; i < 4; ++i) {
        double av = aw[rq*4 + i][k];
        ac0[i] = fma(av, w0, ac0[i]);
        ac1[i] = fma(av, w1, ac1[i]);
      }
    }
    double hv[4];
    unsigned keA = keys[2 + 4*s], keB = keys[2 + 4*s + 1];
    #pragma unroll
    for (int i = 0; i < 4; ++i) {
      int row = rq*4 + i, R = r0 + row, b = R & 31;
      double mu  = ac0[i] + xn[b*256 + c2] + bnn[c2];
      double var = ac1[i] + xn[b*256 + c2 + 128] + bnn[c2 + 128];
      double sp = fmax(var, 0.0) + log1p(exp(-fabs(var)));
      double ep = eps_normal(keA, keB, (unsigned)(R*128 + c2));
      double n  = fma(ep, sp, mu);
      hv[i] = (1.0 - zrv[i])*n + zrv[i]*ah[row][c2];
      h1out[(size_t)R*128 + c2] = hv[i];
    }
    __syncthreads();
    #pragma unroll
    for (int i = 0; i < 4; ++i) aw[rq*4 + i][c2] = hv[i];
  }
#endif
  __syncthreads();   // aw = h1 visible to all
  // ---- logpdf partial (without +p): 8 waves x 2 rows ----
  {
    #pragma unroll
    for (int q = 0; q < 2; ++q) {
      int row = wv*2 + q, R = r0 + row, b = R & 31;
      double part = fma(aw[row][lane], wo[lane], aw[row][lane + 64] * wo[lane + 64]);
      for (int d = 32; d; d >>= 1) part += __shfl_xor(part, d, 64);
      if (lane == 0) LP[b*128 + (R >> 5)] = part + xo[b] + bo[0];
    }
  }
}

// k_sr: barrier-free per-wave softmax + Gumbel-argmax.
__global__ __launch_bounds__(512, 4) void k_sr(
    const double* __restrict__ LP, const double* __restrict__ P,
    const unsigned* __restrict__ keys, int s,
    int* __restrict__ idx, double* __restrict__ PNPRE)
{
  int t = threadIdx.x;
  int wv = t >> 6, lane = t & 63;
  int rw = blockIdx.x * 8 + wv;
  int bw = rw & 31;
  unsigned kA = keys[2 + 4*s + 2], kB = keys[2 + 4*s + 3];
  double v0 = LP[bw*128 + lane]      + P[bw*128 + lane];
  double v1 = LP[bw*128 + lane + 64] + P[bw*128 + lane + 64];
  double m0 = v0, m1 = v1;
  for (int d = 32; d; d >>= 1) {
    m0 = fmax(m0, __shfl_xor(m0, d, 64));
    m1 = fmax(m1, __shfl_xor(m1, d, 64));
  }
  double m = fmax(m0, m1);
  double e0 = exp(v0 - m), e1 = exp(v1 - m);
  double s0 = e0, s1 = e1;
  for (int d = 32; d; d >>= 1) {
    s0 += __shfl_xor(s0, d, 64);
    s1 += __shfl_xor(s1, d, 64);
  }
  double lse = log(s0 + s1);
  double p1_0 = v0 - m - lse;
  double p1_1 = v1 - m - lse;
  double lg0 = log(0.5*exp(p1_0) + 0.00390625);
  double lg1 = log(0.5*exp(p1_1) + 0.00390625);
  double g0 = gumbel_d(kA, kB, (unsigned)(rw*128 + lane)) + lg0;
  double g1 = gumbel_d(kA, kB, (unsigned)(rw*128 + lane + 64)) + lg1;
  double val; int bj;
  if (g0 >= g1) { val = g0; bj = lane; } else { val = g1; bj = lane + 64; }
  for (int d = 32; d; d >>= 1) {
    double ov = __shfl_xor(val, d, 64);
    int    oj = __shfl_xor(bj, d, 64);
    if (ov > val || (ov == val && oj < bj)) { val = ov; bj = oj; }
  }
  double pl = __shfl(p1_0, bj & 63, 64);
  double ph = __shfl(p1_1, bj & 63, 64);
  if (lane == 0) {
    idx[rw] = bj;
    double p1b = (bj < 64) ? pl : ph;
    double pe = exp(p1b);
    PNPRE[bw*128 + (rw >> 5)] = log(pe / (0.5*pe + 0.00390625));
  }
}

// k_yfinal: phase C for step 99 (32 blocks x 512)
__global__ __launch_bounds__(512) void k_yfinal(
    const double* __restrict__ hlast, const int* __restrict__ idxp,
    const double* __restrict__ PNPRE, double* __restrict__ P,
    const double* __restrict__ h2lw, const double* __restrict__ h2lb,
    float* __restrict__ yout)
{
  __shared__ double wsh[128], ys[128], red8[8][128];
  __shared__ int    isx[128];
  __shared__ double smx[2], ssx[2];
  int t = threadIdx.x, b = blockIdx.x;
  int wv = t >> 6, lane = t & 63;
  if (t < 128) {
    double q = PNPRE[b*128 + t];
    double m = q;
    for (int d = 32; d; d >>= 1) m = fmax(m, __shfl_xor(m, d, 64));
    if ((t & 63) == 0) smx[t >> 6] = m;
  }
  __syncthreads();
  if (t < 128) {
    double q = PNPRE[b*128 + t];
    double m = fmax(smx[0], smx[1]);
    double e = exp(q - m), su = e;
    for (int d = 32; d; d >>= 1) su += __shfl_xor(su, d, 64);
    if ((t & 63) == 0) ssx[t >> 6] = su;
  }
  __syncthreads();
  if (t < 128) {
    double q = PNPRE[b*128 + t];
    double m = fmax(smx[0], smx[1]);
    double pn = q - (m + log(ssx[0] + ssx[1]));
    P[b*128 + t] = pn;
    wsh[t] = exp(pn);
    isx[t] = idxp[t*32 + b];
  }
  __syncthreads();
  #pragma unroll
  for (int colh = 0; colh < 2; ++colh) {
    int col = lane + colh*64;
    double acc = 0.0;
    for (int q = 0; q < 16; ++q) {
      int ii = wv*16 + q;
      acc = fma(wsh[ii], hlast[(size_t)(isx[ii]*32 + b)*128 + col], acc);
    }
    red8[wv][col] = acc;
  }
  __syncthreads();
  if (t < 128) {
    double a = red8[0][t];
    for (int gg = 1; gg < 8; ++gg) a += red8[gg][t];
    ys[t] = a;
  }
  __syncthreads();
  if (t < 3) {
    double dsum = h2lb[t];
    for (int cc = 0; cc < 128; ++cc)
      dsum = fma(h2lw[t*128 + cc], ys[cc], dsum);
    yout[99*96 + b*3 + t] = (float)(1.0 / (1.0 + exp(-dsum)));
  }
}

// epilogue: pf for the last step (gather via idx)
__global__ __launch_bounds__(256) void k_pfend(const double* __restrict__ h1,
    const int* __restrict__ idx, const double* __restrict__ h2lw,
    const double* __restrict__ h2lb, float* __restrict__ pfout)
{
  int wv = threadIdx.x >> 6, lane = threadIdx.x & 63;
  int r = blockIdx.x * 4 + wv;
  int b = r & 31;
  const double* hr = h1 + (size_t)(idx[r]*32 + b) * 128;
  double v0 = hr[lane*2], v1 = hr[lane*2 + 1];
  double s0 = fma(v0, h2lw[lane*2],       v1 * h2lw[lane*2 + 1]);
  double s1 = fma(v0, h2lw[128 + lane*2], v1 * h2lw[128 + lane*2 + 1]);
  double s2 = fma(v0, h2lw[256 + lane*2], v1 * h2lw[256 + lane*2 + 1]);
  for (int d = 32; d; d >>= 1) {
    s0 += __shfl_xor(s0, d, 64);
    s1 += __shfl_xor(s1, d, 64);
    s2 += __shfl_xor(s2, d, 64);
  }
  if (lane == 0) {
    float* o = pfout + r * 3;
    o[0] = (float)(1.0 / (1.0 + exp(-(s0 + h2lb[0]))));
    o[1] = (float)(1.0 / (1.0 + exp(-(s1 + h2lb[1]))));
    o[2] = (float)(1.0 / (1.0 + exp(-(s2 + h2lb[2]))));
  }
}

// ===================== host launch =====================
extern "C" void kernel_launch(void* const* d_in, const int* in_sizes, int n_in,
                              void* d_out, int out_size, void* d_ws, size_t ws_size,
                              hipStream_t stream)
{
  (void)in_sizes; (void)n_in; (void)out_size; (void)ws_size;
  const float* map_in = (const float*)d_in[0];
  const float* obs_in = (const float*)d_in[1];
  const float* act_in = (const float*)d_in[2];
  const float* c1_w = (const float*)d_in[3];
  const float* c1_g = (const float*)d_in[4];
  const float* c1_b = (const float*)d_in[5];
  const float* c2_w = (const float*)d_in[6];
  const float* c2_g = (const float*)d_in[7];
  const float* c2_b = (const float*)d_in[8];
  const float* c3_w = (const float*)d_in[9];
  const float* c3_g = (const float*)d_in[10];
  const float* c3_b = (const float*)d_in[11];
  const float* map_w = (const float*)d_in[12];
  const float* map_b = (const float*)d_in[13];
  const float* m2o_w = (const float*)d_in[14];
  const float* m2o_b = (const float*)d_in[15];
  const float* m2a_w = (const float*)d_in[16];
  const float* m2a_b = (const float*)d_in[17];
  const float* obs_w = (const float*)d_in[18];
  const float* obs_b = (const float*)d_in[19];
  const float* act_w = (const float*)d_in[20];
  const float* act_b = (const float*)d_in[21];
  const float* fcz_w = (const float*)d_in[22];
  const float* fcz_b = (const float*)d_in[23];
  const float* fcr_w = (const float*)d_in[24];
  const float* fcr_b = (const float*)d_in[25];
  const float* fcn_w = (const float*)d_in[26];
  const float* fcn_b = (const float*)d_in[27];
  const float* fco_w = (const float*)d_in[28];
  const float* fco_b = (const float*)d_in[29];
  const float* h2l_w = (const float*)d_in[30];
  const float* h2l_b = (const float*)d_in[31];

  float* yout  = (float*)d_out;
  float* pfout = (float*)d_out + 9600;

  char* ws = (char*)d_ws;
  double*   H0     = (double*)(ws + 0);           // 4096*128
  double*   H1A    = (double*)(ws + 4194304);
  double*   H1B    = (double*)(ws + 8388608);
  double*   XS     = (double*)(ws + 12582912);    // 100*32*128
  double*   C1O    = (double*)(ws + 15859712);    // 32*16*1024
  double*   C2O    = (double*)(ws + 20054016);    // 32*32*1024
  double*   C3O    = (double*)(ws + 28442624);    // 32*32*1024
  double*   XZR    = (double*)(ws + 15859712);    // 100*32*256 (overlay)
  double*   XN     = (double*)(ws + 22413312);    // 100*32*256 (overlay)
  double*   XO     = (double*)(ws + 28966912);    // 100*32     (overlay)
  double*   WZRT   = (double*)(ws + 36831232);    // 256*256
  double*   WNT    = (double*)(ws + 37355520);
  double*   WO     = (double*)(ws + 37879808);
  double*   BZ     = (double*)(ws + 37881856);
  double*   BR     = (double*)(ws + 37882880);
  double*   BNN    = (double*)(ws + 37883904);
  double*   BO     = (double*)(ws + 37885952);
  double*   H2LW   = (double*)(ws + 37886208);
  double*   H2LB   = (double*)(ws + 37889280);
  double*   EMB    = (double*)(ws + 37889536);    // 32*128
  double*   OMAP   = (double*)(ws + 37922304);    // 32*64
  double*   AMAP   = (double*)(ws + 37938688);
  double*   P      = (double*)(ws + 37955072);    // 4096  [b][p]
  double*   LP     = (double*)(ws + 37987840);    // 4096  [b][p]
  int*      IDX    = (int*)   (ws + 38020608);    // 4096  [p*32+b]
  unsigned* KEYS   = (unsigned*)(ws + 38036992);  // 402
  double*   SCSH   = (double*)(ws + 38039040);    // 32*2
  double*   PARTS  = (double*)(ws + 38039552);    // 256
  double*   PARTS2 = (double*)(ws + 38041600);    // 256
  double*   PNPRE  = (double*)(ws + 38043648);    // 4096  [b][p]

  // ---- setup ----
  k_keys<<<1, 64, 0, stream>>>(KEYS);
  k_prep<<<517, 256, 0, stream>>>(fcz_w, fcz_b, fcr_w, fcr_b, fcn_w, fcn_b,
                                  fco_w, fco_b, h2l_w, h2l_b,
                                  WZRT, WNT, WO, BZ, BR, BNN, BO, H2LW, H2LB);
  k_h0<<<2048, 256, 0, stream>>>(KEYS, H0, P);

  // ---- frontend ----
  k_conv1<<<512, 256, 0, stream>>>(map_in, c1_w, C1O);
  k_bnstats1<<<128, 256, 0, stream>>>(C1O, PARTS, PARTS2, 16);
  k_bnstats2<<<1, 32, 0, stream>>>(PARTS, PARTS2, c1_g, c1_b, SCSH, 16);
  k_bnapply<<<2048, 256, 0, stream>>>(C1O, SCSH, 16);
  k_conv3x3<<<256, 256, 0, stream>>>(C1O, c2_w, C2O, 16, 32);
  k_bnstats1<<<256, 256, 0, stream>>>(C2O, PARTS, PARTS2, 32);
  k_bnstats2<<<1, 32, 0, stream>>>(PARTS, PARTS2, c2_g, c2_b, SCSH, 32);
  k_bnapply<<<4096, 256, 0, stream>>>(C2O, SCSH, 32);
  k_conv3x3<<<256, 256, 0, stream>>>(C2O, c3_w, C3O, 32, 32);
  k_bnstats1<<<256, 256, 0, stream>>>(C3O, PARTS, PARTS2, 32);
  k_bnstats2<<<1, 32, 0, stream>>>(PARTS, PARTS2, c3_g, c3_b, SCSH, 32);
  k_bnapply<<<4096, 256, 0, stream>>>(C3O, SCSH, 32);
  k_mapfc<<<512, 256, 0, stream>>>(C3O, map_w, map_b, EMB);
  k_maps<<<32, 64, 0, stream>>>(EMB, m2o_w, m2o_b, m2a_w, m2a_b, OMAP, AMAP);
  {
    dim3 g(100, 32);
    k_xs<<<g, 128, 0, stream>>>(obs_in, act_in, obs_w, obs_b, act_w, act_b,
                                OMAP, AMAP, WO, XS, XO);
  }
  k_xpre2<<<400, 256, 0, stream>>>(XS, WZRT, WNT, XZR, XN);

  // ---- scan over 100 timesteps (2 kernels/step) ----
  double* hb[2] = { H1A, H1B };
  for (int s = 0; s < 100; ++s) {
    const double* hsrc = (s == 0) ? H0 : hb[(s - 1) & 1];
    const int* idxp = (s == 0) ? nullptr : IDX;
    float* pfprev = (s == 0) ? nullptr : (pfout + (size_t)(s - 1) * 12288);
    k_step<<<256, 512, 0, stream>>>(hsrc, idxp,
        XZR + (size_t)s*32*256, XN + (size_t)s*32*256, XO + (size_t)s*32,
        WZRT, WNT, BZ, BR, BNN, WO, BO, P, H2LW, H2LB,
        hb[s & 1], LP, PNPRE, pfprev, yout, KEYS, s);
    k_sr<<<512, 512, 0, stream>>>(LP, P, KEYS, s, IDX, PNPRE);
  }
  k_yfinal<<<32, 512, 0, stream>>>(hb[1], IDX, PNPRE, P, H2LW, H2LB, yout);
  k_pfend<<<1024, 256, 0, stream>>>(hb[1], IDX, H2LW, H2LB,
                                    pfout + (size_t)99 * 12288);
}

// Round 14
// 4962.615 us; speedup vs baseline: 1.0063x; 1.0063x over previous
//
#include <hip/hip_runtime.h>
#include <math.h>

typedef double double2v __attribute__((ext_vector_type(2)));
typedef double double4v __attribute__((ext_vector_type(4)));
typedef float  float4v  __attribute__((ext_vector_type(4)));

#if defined(__has_builtin)
#if __has_builtin(__builtin_amdgcn_mfma_f64_16x16x4f64)
#define HAVE_MFMA_F64 1
#endif
#endif

// ===================== JAX Threefry-2x32 (bit-exact) =====================
__device__ __forceinline__ void threefry2x32(unsigned k0, unsigned k1,
                                             unsigned x0, unsigned x1,
                                             unsigned& o0, unsigned& o1)
{
  unsigned ks2 = k0 ^ k1 ^ 0x1BD11BDAu;
  x0 += k0; x1 += k1;
#define TFR(r) { x0 += x1; x1 = (x1 << r) | (x1 >> (32 - r)); x1 ^= x0; }
  TFR(13) TFR(15) TFR(26) TFR(6)
  x0 += k1;  x1 += ks2 + 1u;
  TFR(17) TFR(29) TFR(16) TFR(24)
  x0 += ks2; x1 += k0 + 2u;
  TFR(13) TFR(15) TFR(26) TFR(6)
  x0 += k0;  x1 += k1 + 3u;
  TFR(17) TFR(29) TFR(16) TFR(24)
  x0 += k1;  x1 += ks2 + 4u;
  TFR(13) TFR(15) TFR(26) TFR(6)
  x0 += ks2; x1 += k0 + 5u;
#undef TFR
  o0 = x0; o1 = x1;
}

// jax_threefry_partitionable=True: word e = o0 ^ o1 of block (0, e)
__device__ __forceinline__ unsigned rand_word(unsigned kA, unsigned kB, unsigned e)
{
  unsigned o0, o1;
  threefry2x32(kA, kB, 0u, e, o0, o1);
  return o0 ^ o1;
}

__device__ __forceinline__ float bits_to_unit(unsigned bits)
{
  unsigned u = (bits >> 9) | 0x3f800000u;
  return __uint_as_float(u) - 1.0f;   // exact, in [0,1)
}

// erfinv in double: Giles poly init + 1 Halley iteration on erf()
__device__ __forceinline__ double erfinv_d(double x)
{
  double w = -log((1.0 - x) * (1.0 + x));
  double p;
  if (w < 5.0) {
    w -= 2.5;
    p = 2.81022636e-08;
    p = fma(p, w, 3.43273939e-07);
    p = fma(p, w, -3.5233877e-06);
    p = fma(p, w, -4.39150654e-06);
    p = fma(p, w, 0.00021858087);
    p = fma(p, w, -0.00125372503);
    p = fma(p, w, -0.00417768164);
    p = fma(p, w, 0.246640727);
    p = fma(p, w, 1.50140941);
  } else {
    w = sqrt(w) - 3.0;
    p = -0.000200214257;
    p = fma(p, w, 0.000100950558);
    p = fma(p, w, 0.00134934322);
    p = fma(p, w, -0.00367342844);
    p = fma(p, w, 0.00573950773);
    p = fma(p, w, -0.0076224613);
    p = fma(p, w, 0.00943887047);
    p = fma(p, w, 1.00167406);
    p = fma(p, w, 2.83297682);
  }
  double r = p * x;
  double f  = erf(r) - x;
  double fp = 1.1283791670955126 * exp(-r * r);   // 2/sqrt(pi) e^{-r^2}
  double q  = f / fp;
  return r - q / (1.0 + r * q);
}

// N(0,1) sample e of a jax.random.normal(f32) draw
__device__ __forceinline__ double eps_normal(unsigned kA, unsigned kB, unsigned e)
{
  float f = bits_to_unit(rand_word(kA, kB, e));
  double u = (double)f * (2.0 - 5.9604644775390625e-8)
           - (1.0 - 5.9604644775390625e-8);
  return 1.4142135623730951 * erfinv_d(u);
}

__device__ __forceinline__ double sigd(double x) { return 1.0 / (1.0 + exp(-x)); }

__device__ __forceinline__ double gumbel_d(unsigned kA, unsigned kB, unsigned e)
{
  float f = bits_to_unit(rand_word(kA, kB, e));
  double u = (f == 0.0f) ? 1.1754943508222875e-38 : (double)f;
  return -log(-log(u));
}

// ===================== setup kernels =====================
__global__ void k_keys(unsigned* keys)
{
  if (threadIdx.x != 0 || blockIdx.x != 0) return;
  unsigned a0,a1,b0,b1,c0,c1,d0,d1;
  unsigned kx = 0u, ky = 42u;                 // jax.random.key(42)
  threefry2x32(kx, ky, 0u, 0u, a0, a1);       // carried key
  threefry2x32(kx, ky, 0u, 1u, b0, b1);       // k0 (h0 uniform)
  keys[0] = b0; keys[1] = b1;
  kx = a0; ky = a1;
  for (int s = 0; s < 100; ++s) {
    threefry2x32(kx, ky, 0u, 0u, a0, a1);     // k
    threefry2x32(kx, ky, 0u, 1u, c0, c1);     // ke
    threefry2x32(kx, ky, 0u, 2u, d0, d1);     // kr
    keys[2 + 4*s + 0] = c0; keys[2 + 4*s + 1] = c1;
    keys[2 + 4*s + 2] = d0; keys[2 + 4*s + 3] = d1;
    kx = a0; ky = a1;
  }
}

__global__ __launch_bounds__(256) void k_prep(
    const float* fcz_w, const float* fcz_b, const float* fcr_w, const float* fcr_b,
    const float* fcn_w, const float* fcn_b, const float* fco_w, const float* fco_b,
    const float* h2l_w, const float* h2l_b,
    double* wzrT, double* wnT, double* wo, double* bz, double* br,
    double* bnn, double* bo, double* h2lw, double* h2lb)
{
  int id = blockIdx.x * 256 + threadIdx.x;
  if (id < 65536) {
    int k = id >> 8, j = id & 255;
    wzrT[id] = (double)((j < 128) ? fcz_w[j*256 + k] : fcr_w[(j-128)*256 + k]);
    return;
  }
  id -= 65536;
  if (id < 65536) { int k = id >> 8, j = id & 255; wnT[id] = (double)fcn_w[j*256 + k]; return; }
  id -= 65536;
  if (id < 256) { wo[id] = (double)fco_w[id]; return; }
  id -= 256;
  if (id < 128) { bz[id] = (double)fcz_b[id]; return; }
  id -= 128;
  if (id < 128) { br[id] = (double)fcr_b[id]; return; }
  id -= 128;
  if (id < 256) { bnn[id] = (double)fcn_b[id]; return; }
  id -= 256;
  if (id < 1) { bo[0] = (double)fco_b[0]; return; }
  id -= 1;
  if (id < 384) { h2lw[id] = (double)h2l_w[id]; return; }
  id -= 384;
  if (id < 3) { h2lb[id] = (double)h2l_b[id]; return; }
}

__global__ __launch_bounds__(256) void k_h0(const unsigned* keys, double* h, double* p)
{
  unsigned e = blockIdx.x * 256 + threadIdx.x;    // < 524288
  h[e] = (double)bits_to_unit(rand_word(keys[0], keys[1], e));
  if (e < 4096) p[e] = (double)(float)log(1.0 / 128.0);
}

// ===================== frontend (map CNN encoder) =====================
__global__ __launch_bounds__(256) void k_conv1(const float* in, const float* w, double* out)
{
  int bc = blockIdx.x; int b = bc >> 4, co = bc & 15;
  __shared__ double wl[25];
  __shared__ float plf[4096];
  if (threadIdx.x < 25) wl[threadIdx.x] = (double)w[co*25 + threadIdx.x];
  const float* ib = in + (size_t)b * 4096;
  for (int j = 0; j < 16; ++j) plf[threadIdx.x + j*256] = ib[threadIdx.x + j*256];
  __syncthreads();
  for (int q = 0; q < 4; ++q) {
    int px = q*256 + threadIdx.x;
    int oh = px >> 5, ow = px & 31;
    double acc = 0.0;
    for (int kh = 0; kh < 5; ++kh) {
      int ih = oh*2 - 2 + kh; if (ih < 0 || ih >= 64) continue;
      for (int kw = 0; kw < 5; ++kw) {
        int iw = ow*2 - 2 + kw; if (iw < 0 || iw >= 64) continue;
        acc = fma((double)plf[ih*64 + iw], wl[kh*5 + kw], acc);
      }
    }
    out[((size_t)b*16 + co)*1024 + px] = fmax(acc, 0.0);
  }
}

// 2 output channels per block; BN of the INPUT layer applied at LDS staging
__global__ __launch_bounds__(256) void k_conv3x3(const double* in, const float* w,
                                                 const double* __restrict__ scsh,
                                                 double* out, int Ci, int Co)
{
  int bc = blockIdx.x; int b = bc / (Co >> 1), cop = bc % (Co >> 1);
  int co0 = cop * 2;
  __shared__ double wl0[288], wl1[288];
  __shared__ double pl[2][1024];
  for (int e = threadIdx.x; e < Ci*9; e += 256) {
    wl0[e] = (double)w[(size_t)co0*Ci*9 + e];
    wl1[e] = (double)w[(size_t)(co0 + 1)*Ci*9 + e];
  }
  double acc0[4] = {0.0, 0.0, 0.0, 0.0};
  double acc1[4] = {0.0, 0.0, 0.0, 0.0};
  const double* ib = in + (size_t)b * Ci * 1024;
  {
    double sc = scsh[0], sh = scsh[1];
    for (int q = 0; q < 4; ++q)
      pl[0][threadIdx.x + q*256] = fma(ib[threadIdx.x + q*256], sc, sh);
  }
  __syncthreads();
  for (int ci = 0; ci < Ci; ++ci) {
    int cur = ci & 1;
    if (ci + 1 < Ci) {
      double sc = scsh[(ci + 1)*2], sh = scsh[(ci + 1)*2 + 1];
      for (int q = 0; q < 4; ++q)
        pl[cur ^ 1][threadIdx.x + q*256] =
            fma(ib[(ci + 1)*1024 + threadIdx.x + q*256], sc, sh);
    }
    const double* wp0 = wl0 + ci*9;
    const double* wp1 = wl1 + ci*9;
    for (int q = 0; q < 4; ++q) {
      int px = q*256 + threadIdx.x;
      int oh = px >> 5, ow = px & 31;
      double a0 = acc0[q], a1 = acc1[q];
      for (int kh = 0; kh < 3; ++kh) {
        int ih = oh - 1 + kh; if (ih < 0 || ih >= 32) continue;
        for (int kw = 0; kw < 3; ++kw) {
          int iw = ow - 1 + kw; if (iw < 0 || iw >= 32) continue;
          double pv = pl[cur][ih*32 + iw];
          a0 = fma(pv, wp0[kh*3 + kw], a0);
          a1 = fma(pv, wp1[kh*3 + kw], a1);
        }
      }
      acc0[q] = a0; acc1[q] = a1;
    }
    __syncthreads();
  }
  for (int q = 0; q < 4; ++q) {
    int px = q*256 + threadIdx.x;
    out[((size_t)b*Co + co0)*1024 + px]     = fmax(acc0[q], 0.0);
    out[((size_t)b*Co + co0 + 1)*1024 + px] = fmax(acc1[q], 0.0);
  }
}

__global__ __launch_bounds__(256) void k_bnstats1(const double* __restrict__ x,
    double* __restrict__ partS, double* __restrict__ partS2, int C)
{
  int c = blockIdx.x >> 3, chunk = blockIdx.x & 7;
  double s = 0.0, s2 = 0.0;
  for (int e = threadIdx.x; e < 4096; e += 256) {
    int b = chunk*4 + (e >> 10), px = e & 1023;
    double v = x[((size_t)b*C + c)*1024 + px];
    s += v; s2 = fma(v, v, s2);
  }
  __shared__ double rs[256], rs2[256];
  rs[threadIdx.x] = s; rs2[threadIdx.x] = s2;
  __syncthreads();
  for (int d = 128; d; d >>= 1) {
    if (threadIdx.x < d) { rs[threadIdx.x] += rs[threadIdx.x + d]; rs2[threadIdx.x] += rs2[threadIdx.x + d]; }
    __syncthreads();
  }
  if (threadIdx.x == 0) { partS[blockIdx.x] = rs[0]; partS2[blockIdx.x] = rs2[0]; }
}

__global__ void k_bnstats2(const double* __restrict__ partS,
                           const double* __restrict__ partS2,
                           const float* g, const float* bta, double* scsh, int C)
{
  int c = threadIdx.x;
  if (c >= C) return;
  double s = 0.0, s2 = 0.0;
  for (int j = 0; j < 8; ++j) { s += partS[c*8 + j]; s2 += partS2[c*8 + j]; }
  double n = 32768.0;
  double mean = s / n;
  double var = s2 / n - mean*mean;
  double sc = (double)g[c] / sqrt(var + 1e-5);
  scsh[c*2] = sc;
  scsh[c*2 + 1] = (double)bta[c] - mean * sc;
}

// vectorized; BN of layer 3 applied at x load
__global__ __launch_bounds__(256) void k_mapfc(const double* x, const float* w,
                                               const double* __restrict__ scsh,
                                               const float* bias, double* emb)
{
  int blk = blockIdx.x; int b = blk >> 4, jg = blk & 15;
  double acc[8];
  #pragma unroll
  for (int jj = 0; jj < 8; ++jj) acc[jj] = 0.0;
  const double* xb = x + (size_t)b * 32768;
  for (int j = 0; j < 32; ++j) {
    int e4 = (threadIdx.x + j*256) << 2;
    int c = e4 >> 10;                       // channel (4-elem group never crosses)
    double sc = scsh[c*2], sh = scsh[c*2 + 1];
    double4v xv = *(const double4v*)&xb[e4];
    xv.x = fma(xv.x, sc, sh);
    xv.y = fma(xv.y, sc, sh);
    xv.z = fma(xv.z, sc, sh);
    xv.w = fma(xv.w, sc, sh);
    #pragma unroll
    for (int jj = 0; jj < 8; ++jj) {
      float4v wv = *(const float4v*)&w[(size_t)(jg*8 + jj)*32768 + e4];
      double a = acc[jj];
      a = fma(xv.x, (double)wv.x, a);
      a = fma(xv.y, (double)wv.y, a);
      a = fma(xv.z, (double)wv.z, a);
      a = fma(xv.w, (double)wv.w, a);
      acc[jj] = a;
    }
  }
  __shared__ double red[8][256];
  #pragma unroll
  for (int jj = 0; jj < 8; ++jj) red[jj][threadIdx.x] = acc[jj];
  __syncthreads();
  for (int d = 128; d; d >>= 1) {
    if (threadIdx.x < d)
      #pragma unroll
      for (int jj = 0; jj < 8; ++jj) red[jj][threadIdx.x] += red[jj][threadIdx.x + d];
    __syncthreads();
  }
  if (threadIdx.x < 8) {
    int j = jg*8 + threadIdx.x;
    emb[b*128 + j] = fmax(red[threadIdx.x][0] + (double)bias[j], 0.0);
  }
}

__global__ void k_maps(const double* emb, const float* m2o_w, const float* m2o_b,
                       const float* m2a_w, const float* m2a_b,
                       double* omap, double* amap)
{
  int b = blockIdx.x, j = threadIdx.x;   // 64 threads
  double a1 = (double)m2o_b[j], a2 = (double)m2a_b[j];
  for (int k = 0; k < 128; ++k) {
    double ev = emb[b*128 + k];
    a1 = fma(ev, (double)m2o_w[j*128 + k], a1);
    a2 = fma(ev, (double)m2a_w[j*128 + k], a2);
  }
  omap[b*64 + j] = fmax(a1, 0.0);
  amap[b*64 + j] = fmax(a2, 0.0);
}

__global__ __launch_bounds__(128) void k_xs(const float* obs_in, const float* act_in,
                                            const float* obs_w, const float* obs_b,
                                            const float* act_w, const float* act_b,
                                            const double* omap, const double* amap,
                                            const double* wo,
                                            double* xs, double* xo)
{
  int s = blockIdx.x, b = blockIdx.y, j = threadIdx.x;
  double v;
  if (j < 64) {
    double a = (double)obs_b[j];
    const float* o = obs_in + ((size_t)b*100 + s)*16;
    for (int k = 0; k < 16; ++k) a = fma((double)o[k], (double)obs_w[j*16 + k], a);
    v = fmax(a, 0.0) * omap[b*64 + j];
  } else {
    int j2 = j - 64;
    double a = (double)act_b[j2];
    const float* o = act_in + ((size_t)b*100 + s)*3;
    for (int k = 0; k < 3; ++k) a = fma((double)o[k], (double)act_w[j2*3 + k], a);
    v = fmax(a, 0.0) * amap[b*64 + j2];
  }
  xs[((size_t)s*32 + b)*128 + j] = v;
  __shared__ double red[128];
  red[j] = v * wo[128 + j];
  __syncthreads();
  for (int d = 64; d; d >>= 1) {
    if (j < d) red[j] += red[j + d];
    __syncthreads();
  }
  if (j == 0) xo[s*32 + b] = red[0];
}

__global__ __launch_bounds__(256, 2) void k_xpre2(const double* __restrict__ xs,
    const double* __restrict__ wzrT, const double* __restrict__ wnT,
    double* __restrict__ xzr, double* __restrict__ xn)
{
  int s = blockIdx.x >> 2, bg = blockIdx.x & 3;
  __shared__ double xl[8][128];
  int t = threadIdx.x;
  #pragma unroll
  for (int j = 0; j < 4; ++j) {
    int e = t + j*256;
    int i = e >> 7, cc = e & 127;
    xl[i][cc] = xs[((size_t)s*32 + bg*8 + i)*128 + cc];
  }
  __syncthreads();
  double az[8], an[8];
  #pragma unroll
  for (int i = 0; i < 8; ++i) { az[i] = 0.0; an[i] = 0.0; }
  for (int k = 0; k < 128; ++k) {
    double wz = wzrT[k*256 + t];
    double wn = wnT[(128 + k)*256 + t];
    #pragma unroll
    for (int i = 0; i < 8; ++i) {
      double xv = xl[i][k];
      az[i] = fma(xv, wz, az[i]);
      an[i] = fma(xv, wn, an[i]);
    }
  }
  #pragma unroll
  for (int i = 0; i < 8; ++i) {
    size_t sb = (size_t)s*32 + bg*8 + i;
    xzr[sb*256 + t] = az[i];
    xn [sb*256 + t] = an[i];
  }
}

// ===================== fused scan step (f64 MFMA, layout flag=1 verified) ==
__global__ __launch_bounds__(512, 4) void k_step(
    const double* __restrict__ hsrc, const int* __restrict__ idxp,
    const double* __restrict__ xzr, const double* __restrict__ xn,
    const double* __restrict__ xo,
    const double* __restrict__ wzrT, const double* __restrict__ wnT,
    const double* __restrict__ bz, const double* __restrict__ br,
    const double* __restrict__ bnn, const double* __restrict__ wo,
    const double* __restrict__ bo, double* __restrict__ P,
    const double* __restrict__ h2lw, const double* __restrict__ h2lb,
    double* __restrict__ h1out, double* __restrict__ LP,
    const double* __restrict__ PNPRE,
    float* __restrict__ pfout, float* __restrict__ yout,
    const unsigned* __restrict__ keys, int s)
{
  __shared__ double ah[16][130];   // gathered h
  __shared__ double aw[16][130];   // rg*h, later h1
  __shared__ double wsh[128], ys[128], red8[8][128];
  __shared__ int    isx[128];
  __shared__ double smx[2], ssx[2];
  const int t  = threadIdx.x;
  const int r0 = blockIdx.x * 16;
  const int wv = t >> 6, lane = t & 63;
  const bool first = (idxp == nullptr);

  // ---- phase C of step s-1 (blocks 0..31): pn normalize + y ----
  if (!first && blockIdx.x < 32) {
    int b = blockIdx.x;
    if (t < 128) {
      double q = PNPRE[b*128 + t];
      double m = q;
      for (int d = 32; d; d >>= 1) m = fmax(m, __shfl_xor(m, d, 64));
      if ((t & 63) == 0) smx[t >> 6] = m;
    }
    __syncthreads();
    if (t < 128) {
      double q = PNPRE[b*128 + t];
      double m = fmax(smx[0], smx[1]);
      double e = exp(q - m), su = e;
      for (int d = 32; d; d >>= 1) su += __shfl_xor(su, d, 64);
      if ((t & 63) == 0) ssx[t >> 6] = su;
    }
    __syncthreads();
    if (t < 128) {
      double q = PNPRE[b*128 + t];
      double m = fmax(smx[0], smx[1]);
      double pn = q - (m + log(ssx[0] + ssx[1]));
      P[b*128 + t] = pn;
      wsh[t] = exp(pn);
      isx[t] = idxp[t*32 + b];
    }
    __syncthreads();
    {
      #pragma unroll
      for (int colh = 0; colh < 2; ++colh) {
        int col = lane + colh*64;
        double acc = 0.0;
        for (int q = 0; q < 16; ++q) {
          int ii = wv*16 + q;
          acc = fma(wsh[ii], hsrc[(size_t)(isx[ii]*32 + b)*128 + col], acc);
        }
        red8[wv][col] = acc;
      }
    }
    __syncthreads();
    if (t < 128) {
      double a = red8[0][t];
      for (int gg = 1; gg < 8; ++gg) a += red8[gg][t];
      ys[t] = a;
    }
    __syncthreads();
    if (t < 3) {
      double dsum = h2lb[t];
      for (int cc = 0; cc < 128; ++cc)
        dsum = fma(h2lw[t*128 + cc], ys[cc], dsum);
      yout[(s - 1)*96 + b*3 + t] = (float)(1.0 / (1.0 + exp(-dsum)));
    }
    __syncthreads();
  }

  // ---- gather prev h (4 elements/thread, coalesced) ----
  #pragma unroll
  for (int j = 0; j < 4; ++j) {
    int e = t + j*512;
    int r = e >> 7, cc = e & 127;
    int R = r0 + r, b = R & 31;
    int src = first ? R : (idxp[R]*32 + b);
    ah[r][cc] = hsrc[(size_t)src*128 + cc];
  }
  __syncthreads();
  // ---- pf for previous step: 8 waves x 2 rows ----
  if (pfout != nullptr) {
    #pragma unroll
    for (int q = 0; q < 2; ++q) {
      int i = wv*2 + q;
      double v0 = ah[i][lane*2], v1 = ah[i][lane*2 + 1];
      double s0 = fma(v0, h2lw[lane*2],       v1 * h2lw[lane*2 + 1]);
      double s1 = fma(v0, h2lw[128 + lane*2], v1 * h2lw[128 + lane*2 + 1]);
      double s2 = fma(v0, h2lw[256 + lane*2], v1 * h2lw[256 + lane*2 + 1]);
      for (int d = 32; d; d >>= 1) {
        s0 += __shfl_xor(s0, d, 64);
        s1 += __shfl_xor(s1, d, 64);
        s2 += __shfl_xor(s2, d, 64);
      }
      if (lane == 0) {
        float* o = pfout + (r0 + i) * 3;
        o[0] = (float)(1.0 / (1.0 + exp(-(s0 + h2lb[0]))));
        o[1] = (float)(1.0 / (1.0 + exp(-(s1 + h2lb[1]))));
        o[2] = (float)(1.0 / (1.0 + exp(-(s2 + h2lb[2]))));
      }
    }
  }

#ifdef HAVE_MFMA_F64
  const int mrow = lane & 15;
  const int kgrp = lane >> 4;
  const int col  = wv*16 + mrow;           // this thread's output column
  // ---- GEMM1: h-part of [x|h] @ Wzr^T ----
  double4v acc0 = {0.0, 0.0, 0.0, 0.0};
  double4v acc1 = {0.0, 0.0, 0.0, 0.0};
  for (int k4 = 0; k4 < 32; ++k4) {
    int k = k4*4 + kgrp;
    double a  = ah[mrow][k];
    double b0 = wzrT[(size_t)(128 + k)*256 + col];
    double b1 = wzrT[(size_t)(128 + k)*256 + 128 + col];
    acc0 = __builtin_amdgcn_mfma_f64_16x16x4f64(a, b0, acc0, 0, 0, 0);
    acc1 = __builtin_amdgcn_mfma_f64_16x16x4f64(a, b1, acc1, 0, 0, 0);
  }
  double zq[4];
  #pragma unroll
  for (int q = 0; q < 4; ++q) {
    int row = kgrp + 4*q;
    int b = (r0 + row) & 31;
    zq[q] = sigd(acc0[q] + xzr[b*256 + col] + bz[col]);
    double rgv = sigd(acc1[q] + xzr[b*256 + 128 + col] + br[col]);
    aw[row][col] = rgv * ah[row][col];
  }
  __syncthreads();
  // ---- GEMM2: (rg*h)-part of [rg*h|x] @ Wn^T ----
  acc0 = double4v{0.0, 0.0, 0.0, 0.0};
  acc1 = double4v{0.0, 0.0, 0.0, 0.0};
  for (int k4 = 0; k4 < 32; ++k4) {
    int k = k4*4 + kgrp;
    double a  = aw[mrow][k];
    double b0 = wnT[(size_t)k*256 + col];
    double b1 = wnT[(size_t)k*256 + 128 + col];
    acc0 = __builtin_amdgcn_mfma_f64_16x16x4f64(a, b0, acc0, 0, 0, 0);
    acc1 = __builtin_amdgcn_mfma_f64_16x16x4f64(a, b1, acc1, 0, 0, 0);
  }
  // thread-local reparam + h1
  double hq[4];
  {
    unsigned keA = keys[2 + 4*s], keB = keys[2 + 4*s + 1];
    #pragma unroll
    for (int q = 0; q < 4; ++q) {
      int row = kgrp + 4*q;
      int b = (r0 + row) & 31, R = r0 + row;
      double mu  = acc0[q] + xn[b*256 + col] + bnn[col];
      double var = acc1[q] + xn[b*256 + 128 + col] + bnn[128 + col];
      double sp = fmax(var, 0.0) + log1p(exp(-fabs(var)));
      double ep = eps_normal(keA, keB, (unsigned)(R*128 + col));
      double n  = fma(ep, sp, mu);
      double hv = (1.0 - zq[q])*n + zq[q]*ah[row][col];
      h1out[(size_t)R*128 + col] = hv;
      hq[q] = hv;
    }
  }
  __syncthreads();   // all GEMM2 aw reads complete
  #pragma unroll
  for (int q = 0; q < 4; ++q) aw[kgrp + 4*q][col] = hq[q];
#else
  // compile-time fallback: vector path (R9 bit-exact)
  {
    const int rq = t >> 7;
    const int c2 = t & 127;
    double ac0[4], ac1[4];
    #pragma unroll
    for (int i = 0; i < 4; ++i) { ac0[i] = 0.0; ac1[i] = 0.0; }
    for (int k = 0; k < 128; ++k) {
      double w0 = wzrT[(size_t)(128 + k)*256 + c2];
      double w1 = wzrT[(size_t)(128 + k)*256 + 128 + c2];
      #pragma unroll
      for (int i = 0; i < 4; ++i) {
        double av = ah[rq*4 + i][k];
        ac0[i] = fma(av, w0, ac0[i]);
        ac1[i] = fma(av, w1, ac1[i]);
      }
    }
    double zrv[4];
    #pragma unroll
    for (int i = 0; i < 4; ++i) {
      int row = rq*4 + i, b = (r0 + row) & 31;
      zrv[i] = sigd(ac0[i] + xzr[b*256 + c2] + bz[c2]);
      double rgv = sigd(ac1[i] + xzr[b*256 + c2 + 128] + br[c2]);
      aw[row][c2] = rgv * ah[row][c2];
    }
    __syncthreads();
    #pragma unroll
    for (int i = 0; i < 4; ++i) { ac0[i] = 0.0; ac1[i] = 0.0; }
    for (int k = 0; k < 128; ++k) {
      double w0 = wnT[(size_t)k*256 + c2];
      double w1 = wnT[(size_t)k*256 + 128 + c2];
      #pragma unroll
      for (int i = 0; i < 4; ++i) {
        double av = aw[rq*4 + i][k];
        ac0[i] = fma(av, w0, ac0[i]);
        ac1[i] = fma(av, w1, ac1[i]);
      }
    }
    double hv[4];
    unsigned keA = keys[2 + 4*s], keB = keys[2 + 4*s + 1];
    #pragma unroll
    for (int i = 0; i < 4; ++i) {
      int row = rq*4 + i, R = r0 + row, b = R & 31;
      double mu  = ac0[i] + xn[b*256 + c2] + bnn[c2];
      double var = ac1[i] + xn[b*256 + c2 + 128] + bnn[c2 + 128];
      double sp = fmax(var, 0.0) + log1p(exp(-fabs(var)));
      double ep = eps_normal(keA, keB, (unsigned)(R*128 + c2));
      double n  = fma(ep, sp, mu);
      hv[i] = (1.0 - zrv[i])*n + zrv[i]*ah[row][c2];
      h1out[(size_t)R*128 + c2] = hv[i];
    }
    __syncthreads();
    #pragma unroll
    for (int i = 0; i < 4; ++i) aw[rq*4 + i][c2] = hv[i];
  }
#endif
  __syncthreads();   // aw = h1 visible to all
  // ---- logpdf partial (without +p): 8 waves x 2 rows ----
  {
    #pragma unroll
    for (int q = 0; q < 2; ++q) {
      int row = wv*2 + q, R = r0 + row, b = R & 31;
      double part = fma(aw[row][lane], wo[lane], aw[row][lane + 64] * wo[lane + 64]);
      for (int d = 32; d; d >>= 1) part += __shfl_xor(part, d, 64);
      if (lane == 0) LP[b*128 + (R >> 5)] = part + xo[b] + bo[0];
    }
  }
}

// k_sr: barrier-free per-wave softmax + Gumbel-argmax.
__global__ __launch_bounds__(512, 4) void k_sr(
    const double* __restrict__ LP, const double* __restrict__ P,
    const unsigned* __restrict__ keys, int s,
    int* __restrict__ idx, double* __restrict__ PNPRE)
{
  int t = threadIdx.x;
  int wv = t >> 6, lane = t & 63;
  int rw = blockIdx.x * 8 + wv;
  int bw = rw & 31;
  unsigned kA = keys[2 + 4*s + 2], kB = keys[2 + 4*s + 3];
  double v0 = LP[bw*128 + lane]      + P[bw*128 + lane];
  double v1 = LP[bw*128 + lane + 64] + P[bw*128 + lane + 64];
  double m0 = v0, m1 = v1;
  for (int d = 32; d; d >>= 1) {
    m0 = fmax(m0, __shfl_xor(m0, d, 64));
    m1 = fmax(m1, __shfl_xor(m1, d, 64));
  }
  double m = fmax(m0, m1);
  double e0 = exp(v0 - m), e1 = exp(v1 - m);
  double s0 = e0, s1 = e1;
  for (int d = 32; d; d >>= 1) {
    s0 += __shfl_xor(s0, d, 64);
    s1 += __shfl_xor(s1, d, 64);
  }
  double lse = log(s0 + s1);
  double p1_0 = v0 - m - lse;
  double p1_1 = v1 - m - lse;
  double lg0 = log(0.5*exp(p1_0) + 0.00390625);
  double lg1 = log(0.5*exp(p1_1) + 0.00390625);
  double g0 = gumbel_d(kA, kB, (unsigned)(rw*128 + lane)) + lg0;
  double g1 = gumbel_d(kA, kB, (unsigned)(rw*128 + lane + 64)) + lg1;
  double val; int bj;
  if (g0 >= g1) { val = g0; bj = lane; } else { val = g1; bj = lane + 64; }
  for (int d = 32; d; d >>= 1) {
    double ov = __shfl_xor(val, d, 64);
    int    oj = __shfl_xor(bj, d, 64);
    if (ov > val || (ov == val && oj < bj)) { val = ov; bj = oj; }
  }
  double pl = __shfl(p1_0, bj & 63, 64);
  double ph = __shfl(p1_1, bj & 63, 64);
  if (lane == 0) {
    idx[rw] = bj;
    double p1b = (bj < 64) ? pl : ph;
    double pe = exp(p1b);
    PNPRE[bw*128 + (rw >> 5)] = log(pe / (0.5*pe + 0.00390625));
  }
}

// k_yfinal: phase C for step 99 (32 blocks x 512)
__global__ __launch_bounds__(512) void k_yfinal(
    const double* __restrict__ hlast, const int* __restrict__ idxp,
    const double* __restrict__ PNPRE, double* __restrict__ P,
    const double* __restrict__ h2lw, const double* __restrict__ h2lb,
    float* __restrict__ yout)
{
  __shared__ double wsh[128], ys[128], red8[8][128];
  __shared__ int    isx[128];
  __shared__ double smx[2], ssx[2];
  int t = threadIdx.x, b = blockIdx.x;
  int wv = t >> 6, lane = t & 63;
  if (t < 128) {
    double q = PNPRE[b*128 + t];
    double m = q;
    for (int d = 32; d; d >>= 1) m = fmax(m, __shfl_xor(m, d, 64));
    if ((t & 63) == 0) smx[t >> 6] = m;
  }
  __syncthreads();
  if (t < 128) {
    double q = PNPRE[b*128 + t];
    double m = fmax(smx[0], smx[1]);
    double e = exp(q - m), su = e;
    for (int d = 32; d; d >>= 1) su += __shfl_xor(su, d, 64);
    if ((t & 63) == 0) ssx[t >> 6] = su;
  }
  __syncthreads();
  if (t < 128) {
    double q = PNPRE[b*128 + t];
    double m = fmax(smx[0], smx[1]);
    double pn = q - (m + log(ssx[0] + ssx[1]));
    P[b*128 + t] = pn;
    wsh[t] = exp(pn);
    isx[t] = idxp[t*32 + b];
  }
  __syncthreads();
  #pragma unroll
  for (int colh = 0; colh < 2; ++colh) {
    int col = lane + colh*64;
    double acc = 0.0;
    for (int q = 0; q < 16; ++q) {
      int ii = wv*16 + q;
      acc = fma(wsh[ii], hlast[(size_t)(isx[ii]*32 + b)*128 + col], acc);
    }
    red8[wv][col] = acc;
  }
  __syncthreads();
  if (t < 128) {
    double a = red8[0][t];
    for (int gg = 1; gg < 8; ++gg) a += red8[gg][t];
    ys[t] = a;
  }
  __syncthreads();
  if (t < 3) {
    double dsum = h2lb[t];
    for (int cc = 0; cc < 128; ++cc)
      dsum = fma(h2lw[t*128 + cc], ys[cc], dsum);
    yout[99*96 + b*3 + t] = (float)(1.0 / (1.0 + exp(-dsum)));
  }
}

// epilogue: pf for the last step (gather via idx)
__global__ __launch_bounds__(256) void k_pfend(const double* __restrict__ h1,
    const int* __restrict__ idx, const double* __restrict__ h2lw,
    const double* __restrict__ h2lb, float* __restrict__ pfout)
{
  int wv = threadIdx.x >> 6, lane = threadIdx.x & 63;
  int r = blockIdx.x * 4 + wv;
  int b = r & 31;
  const double* hr = h1 + (size_t)(idx[r]*32 + b) * 128;
  double v0 = hr[lane*2], v1 = hr[lane*2 + 1];
  double s0 = fma(v0, h2lw[lane*2],       v1 * h2lw[lane*2 + 1]);
  double s1 = fma(v0, h2lw[128 + lane*2], v1 * h2lw[128 + lane*2 + 1]);
  double s2 = fma(v0, h2lw[256 + lane*2], v1 * h2lw[256 + lane*2 + 1]);
  for (int d = 32; d; d >>= 1) {
    s0 += __shfl_xor(s0, d, 64);
    s1 += __shfl_xor(s1, d, 64);
    s2 += __shfl_xor(s2, d, 64);
  }
  if (lane == 0) {
    float* o = pfout + r * 3;
    o[0] = (float)(1.0 / (1.0 + exp(-(s0 + h2lb[0]))));
    o[1] = (float)(1.0 / (1.0 + exp(-(s1 + h2lb[1]))));
    o[2] = (float)(1.0 / (1.0 + exp(-(s2 + h2lb[2]))));
  }
}

// ===================== host launch =====================
extern "C" void kernel_launch(void* const* d_in, const int* in_sizes, int n_in,
                              void* d_out, int out_size, void* d_ws, size_t ws_size,
                              hipStream_t stream)
{
  (void)in_sizes; (void)n_in; (void)out_size; (void)ws_size;
  const float* map_in = (const float*)d_in[0];
  const float* obs_in = (const float*)d_in[1];
  const float* act_in = (const float*)d_in[2];
  const float* c1_w = (const float*)d_in[3];
  const float* c1_g = (const float*)d_in[4];
  const float* c1_b = (const float*)d_in[5];
  const float* c2_w = (const float*)d_in[6];
  const float* c2_g = (const float*)d_in[7];
  const float* c2_b = (const float*)d_in[8];
  const float* c3_w = (const float*)d_in[9];
  const float* c3_g = (const float*)d_in[10];
  const float* c3_b = (const float*)d_in[11];
  const float* map_w = (const float*)d_in[12];
  const float* map_b = (const float*)d_in[13];
  const float* m2o_w = (const float*)d_in[14];
  const float* m2o_b = (const float*)d_in[15];
  const float* m2a_w = (const float*)d_in[16];
  const float* m2a_b = (const float*)d_in[17];
  const float* obs_w = (const float*)d_in[18];
  const float* obs_b = (const float*)d_in[19];
  const float* act_w = (const float*)d_in[20];
  const float* act_b = (const float*)d_in[21];
  const float* fcz_w = (const float*)d_in[22];
  const float* fcz_b = (const float*)d_in[23];
  const float* fcr_w = (const float*)d_in[24];
  const float* fcr_b = (const float*)d_in[25];
  const float* fcn_w = (const float*)d_in[26];
  const float* fcn_b = (const float*)d_in[27];
  const float* fco_w = (const float*)d_in[28];
  const float* fco_b = (const float*)d_in[29];
  const float* h2l_w = (const float*)d_in[30];
  const float* h2l_b = (const float*)d_in[31];

  float* yout  = (float*)d_out;
  float* pfout = (float*)d_out + 9600;

  char* ws = (char*)d_ws;
  double*   H0     = (double*)(ws + 0);           // 4096*128
  double*   H1A    = (double*)(ws + 4194304);
  double*   H1B    = (double*)(ws + 8388608);
  double*   XS     = (double*)(ws + 12582912);    // 100*32*128
  double*   C1O    = (double*)(ws + 15859712);    // 32*16*1024
  double*   C2O    = (double*)(ws + 20054016);    // 32*32*1024
  double*   C3O    = (double*)(ws + 28442624);    // 32*32*1024
  double*   XZR    = (double*)(ws + 15859712);    // 100*32*256 (overlay)
  double*   XN     = (double*)(ws + 22413312);    // 100*32*256 (overlay)
  double*   XO     = (double*)(ws + 28966912);    // 100*32     (overlay)
  double*   WZRT   = (double*)(ws + 36831232);    // 256*256
  double*   WNT    = (double*)(ws + 37355520);
  double*   WO     = (double*)(ws + 37879808);
  double*   BZ     = (double*)(ws + 37881856);
  double*   BR     = (double*)(ws + 37882880);
  double*   BNN    = (double*)(ws + 37883904);
  double*   BO     = (double*)(ws + 37885952);
  double*   H2LW   = (double*)(ws + 37886208);
  double*   H2LB   = (double*)(ws + 37889280);
  double*   EMB    = (double*)(ws + 37889536);    // 32*128
  double*   OMAP   = (double*)(ws + 37922304);    // 32*64
  double*   AMAP   = (double*)(ws + 37938688);
  double*   P      = (double*)(ws + 37955072);    // 4096  [b][p]
  double*   LP     = (double*)(ws + 37987840);    // 4096  [b][p]
  int*      IDX    = (int*)   (ws + 38020608);    // 4096  [p*32+b]
  unsigned* KEYS   = (unsigned*)(ws + 38036992);  // 402
  double*   SCSH   = (double*)(ws + 38039040);    // 32*2
  double*   PARTS  = (double*)(ws + 38039552);    // 256
  double*   PARTS2 = (double*)(ws + 38041600);    // 256
  double*   PNPRE  = (double*)(ws + 38043648);    // 4096  [b][p]

  // ---- setup ----
  k_keys<<<1, 64, 0, stream>>>(KEYS);
  k_prep<<<517, 256, 0, stream>>>(fcz_w, fcz_b, fcr_w, fcr_b, fcn_w, fcn_b,
                                  fco_w, fco_b, h2l_w, h2l_b,
                                  WZRT, WNT, WO, BZ, BR, BNN, BO, H2LW, H2LB);
  k_h0<<<2048, 256, 0, stream>>>(KEYS, H0, P);

  // ---- frontend (BN folded into consumers) ----
  k_conv1<<<512, 256, 0, stream>>>(map_in, c1_w, C1O);
  k_bnstats1<<<128, 256, 0, stream>>>(C1O, PARTS, PARTS2, 16);
  k_bnstats2<<<1, 32, 0, stream>>>(PARTS, PARTS2, c1_g, c1_b, SCSH, 16);
  k_conv3x3<<<512, 256, 0, stream>>>(C1O, c2_w, SCSH, C2O, 16, 32);
  k_bnstats1<<<256, 256, 0, stream>>>(C2O, PARTS, PARTS2, 32);
  k_bnstats2<<<1, 32, 0, stream>>>(PARTS, PARTS2, c2_g, c2_b, SCSH, 32);
  k_conv3x3<<<512, 256, 0, stream>>>(C2O, c3_w, SCSH, C3O, 32, 32);
  k_bnstats1<<<256, 256, 0, stream>>>(C3O, PARTS, PARTS2, 32);
  k_bnstats2<<<1, 32, 0, stream>>>(PARTS, PARTS2, c3_g, c3_b, SCSH, 32);
  k_mapfc<<<512, 256, 0, stream>>>(C3O, map_w, SCSH, map_b, EMB);
  k_maps<<<32, 64, 0, stream>>>(EMB, m2o_w, m2o_b, m2a_w, m2a_b, OMAP, AMAP);
  {
    dim3 g(100, 32);
    k_xs<<<g, 128, 0, stream>>>(obs_in, act_in, obs_w, obs_b, act_w, act_b,
                                OMAP, AMAP, WO, XS, XO);
  }
  k_xpre2<<<400, 256, 0, stream>>>(XS, WZRT, WNT, XZR, XN);

  // ---- scan over 100 timesteps (2 kernels/step) ----
  double* hb[2] = { H1A, H1B };
  for (int s = 0; s < 100; ++s) {
    const double* hsrc = (s == 0) ? H0 : hb[(s - 1) & 1];
    const int* idxp = (s == 0) ? nullptr : IDX;
    float* pfprev = (s == 0) ? nullptr : (pfout + (size_t)(s - 1) * 12288);
    k_step<<<256, 512, 0, stream>>>(hsrc, idxp,
        XZR + (size_t)s*32*256, XN + (size_t)s*32*256, XO + (size_t)s*32,
        WZRT, WNT, BZ, BR, BNN, WO, BO, P, H2LW, H2LB,
        hb[s & 1], LP, PNPRE, pfprev, yout, KEYS, s);
    k_sr<<<512, 512, 0, stream>>>(LP, P, KEYS, s, IDX, PNPRE);
  }
  k_yfinal<<<32, 512, 0, stream>>>(hb[1], IDX, PNPRE, P, H2LW, H2LB, yout);
  k_pfend<<<1024, 256, 0, stream>>>(hb[1], IDX, H2LW, H2LB,
                                    pfout + (size_t)99 * 12288);
}